// Round 22
// baseline (198.676 us; speedup 1.0000x reference)
//
#include <hip/hip_runtime.h>
#include <hip/hip_bf16.h>

typedef __attribute__((ext_vector_type(8))) short short8;
typedef __attribute__((ext_vector_type(4))) float f32x4;
typedef __attribute__((ext_vector_type(4))) unsigned short u16x4;

__device__ __forceinline__ unsigned short f2bf(float f) {
  union { float f; unsigned u; } v; v.f = f;
  unsigned r = v.u + 0x7fffu + ((v.u >> 16) & 1u);
  return (unsigned short)(r >> 16);
}

__device__ __forceinline__ float bf2f(short s) {
  union { unsigned u; float f; } v;
  v.u = ((unsigned)(unsigned short)s) << 16;
  return v.f;
}

// C = A * Bt^T. WM*WN waves, wave-tile (MI*16) x 64, NBUF-deep circular LDS
// staging with counted vmcnt (prefetch stays in flight over MFMA), setprio.
// bn-MAJOR linear block mapping (L2 panel reuse per XCD).
// Pass A: EPI=0, WM=2,WN=4,MI=4,BK=32,NBUF=3 -> 128x256, 72 KB LDS,
//   2 blk/CU. Epilogue: w = exp2(-dist*rt2) -> W bf16 via swizzled LDS
//   bounce -> cached stores. NO denominator work (done by wsum kernel).
// Pass B: EPI=1, WM=2,WN=4,MI=4,BK=64,NBUF=2 -> 128x256. Clean K-loop
//   (no in-loop den: round-21 showed it doubles pass B).
//   Epilogue: out fp32 * 1/(denin+1e-8) via LDS bounce -> NT stores.
// LDS staging swizzle: row r (CH x 16B chunks) holds global chunk c^(r&CMASK)
// at slot c; applied global-side (linear gload_lds dest) + reader-side.
template <int EPI, int WM, int WN, int MI, int BK, int NBUF>
__global__ __launch_bounds__(WM * WN * 64, 4) void rbf_gemm(
    const unsigned short* __restrict__ A, const unsigned short* __restrict__ Bt,
    int Ncols, int K,
    const float* __restrict__ xsq, const float* __restrict__ psq,
    const float* __restrict__ rtemp, unsigned short* __restrict__ Wout,
    const float* __restrict__ denin, float* __restrict__ outp,
    int row0, int ldOut) {
  constexpr int NT = WM * WN * 64;       // threads per block
  constexpr int BM = WM * MI * 16;
  constexpr int BN = WN * 64;
  constexpr int CH = BK / 8;             // 16B chunks per row
  constexpr int CMASK = CH - 1;
  constexpr int AIT = BM * CH / NT;      // A staging iters
  constexpr int BIT = BN * CH / NT;      // B staging iters
  constexpr int LOADS = AIT + BIT;
  constexpr int KS = BK / 32;            // k-frags per step
  constexpr int ASZ = BM * BK;
  constexpr int TSZ = (BM + BN) * BK;    // elems per buffer
  constexpr int BOUNCE = EPI == 1 ? BM * BN * 2 : BM * BN;  // shorts
  constexpr int SELEMS = NBUF * TSZ > BOUNCE ? NBUF * TSZ : BOUNCE;
  __shared__ __align__(16) unsigned short smem[SELEMS];

  const int t = threadIdx.x;
  const int lane = t & 63, wid = t >> 6;
  const int wm = wid / WN, wn = wid % WN;
  const int lr = lane & 15, lg = lane >> 4;

  // bn-major mapping: consecutive blocks share bn and walk bm.
  const int nbm = gridDim.x / (Ncols / BN);
  const int bm = blockIdx.x % nbm;
  const int bn = blockIdx.x / nbm;

  const unsigned short* Ab = A + (size_t)bm * BM * K;
  const unsigned short* Bb = Bt + (size_t)bn * BN * K;

  // staging source pointers (swizzled chunk); bumped by +BK per stage
  const unsigned short* gA[AIT];
  const unsigned short* gB[BIT];
#pragma unroll
  for (int i = 0; i < AIT; ++i) {
    const int idx = i * NT + t;
    const int r = idx / CH, c = idx & CMASK;
    gA[i] = Ab + (size_t)r * K + ((c ^ (r & CMASK)) << 3);
  }
#pragma unroll
  for (int i = 0; i < BIT; ++i) {
    const int idx = i * NT + t;
    const int r = idx / CH, c = idx & CMASK;
    gB[i] = Bb + (size_t)r * K + ((c ^ (r & CMASK)) << 3);
  }
  const int dwave = wid << 9;  // wave-uniform LDS elem base (64 lanes * 16B)

  // fragment LDS element offsets (reader applies same swizzle)
  int offA[MI][KS], offB[4][KS];
#pragma unroll
  for (int mi = 0; mi < MI; ++mi) {
    const int ar = wm * (MI * 16) + mi * 16 + lr;
#pragma unroll
    for (int ks = 0; ks < KS; ++ks)
      offA[mi][ks] = ar * BK + ((((ks << 2) | lg) ^ (ar & CMASK)) << 3);
  }
#pragma unroll
  for (int ni = 0; ni < 4; ++ni) {
    const int br = wn * 64 + ni * 16 + lr;
#pragma unroll
    for (int ks = 0; ks < KS; ++ks)
      offB[ni][ks] = ASZ + br * BK + ((((ks << 2) | lg) ^ (br & CMASK)) << 3);
  }

  f32x4 acc[MI][4];
#pragma unroll
  for (int i = 0; i < MI; ++i)
#pragma unroll
    for (int j = 0; j < 4; ++j) acc[i][j] = (f32x4){0.f, 0.f, 0.f, 0.f};

  // STAGE issues from current gA/gB then bumps them by BK.
#define STAGE(bo)                                                                      \
  do {                                                                                 \
    _Pragma("unroll")                                                                  \
    for (int i = 0; i < AIT; ++i) {                                                    \
      __builtin_amdgcn_global_load_lds(                                                \
          (const __attribute__((address_space(1))) void*)gA[i],                        \
          (__attribute__((address_space(3))) void*)(smem + (bo) + i * (NT * 8) + dwave), \
          16, 0, 0);                                                                   \
      gA[i] += BK;                                                                     \
    }                                                                                  \
    _Pragma("unroll")                                                                  \
    for (int i = 0; i < BIT; ++i) {                                                    \
      __builtin_amdgcn_global_load_lds(                                                \
          (const __attribute__((address_space(1))) void*)gB[i],                        \
          (__attribute__((address_space(3))) void*)(smem + (bo) + ASZ + i * (NT * 8) + dwave), \
          16, 0, 0);                                                                   \
      gB[i] += BK;                                                                     \
    }                                                                                  \
  } while (0)

  const int nsteps = K / BK;
  // prologue: issue NBUF-1 stages
#pragma unroll
  for (int p = 0; p < NBUF - 1; ++p)
    if (p < nsteps) STAGE(p * TSZ);

  int bc = 0, bp = (NBUF - 1) % NBUF;  // current / prefetch-dest buffers
  for (int s = 0; s < nsteps; ++s) {
    if (s + NBUF - 1 < nsteps) {
      STAGE(bp * TSZ);  // prefetch; stays in flight over MFMA
      asm volatile("s_waitcnt vmcnt(%0)" :: "i"((NBUF - 1) * LOADS) : "memory");
    } else if (NBUF >= 3 && s + 1 < nsteps) {
      asm volatile("s_waitcnt vmcnt(%0)" :: "i"(LOADS) : "memory");
    } else {
      asm volatile("s_waitcnt vmcnt(0)" ::: "memory");
    }
    __builtin_amdgcn_s_barrier();       // all waves' stage(s) landed
    const unsigned short* sb = smem + bc * TSZ;
    __builtin_amdgcn_s_setprio(1);
#pragma unroll
    for (int ks = 0; ks < KS; ++ks) {
      short8 af[MI], bf[4];
#pragma unroll
      for (int mi = 0; mi < MI; ++mi) af[mi] = *(const short8*)&sb[offA[mi][ks]];
#pragma unroll
      for (int ni = 0; ni < 4; ++ni) bf[ni] = *(const short8*)&sb[offB[ni][ks]];
#pragma unroll
      for (int mi = 0; mi < MI; ++mi)
#pragma unroll
        for (int ni = 0; ni < 4; ++ni)
          acc[mi][ni] = __builtin_amdgcn_mfma_f32_16x16x32_bf16(af[mi], bf[ni],
                                                                acc[mi][ni], 0, 0, 0);
    }
    __builtin_amdgcn_s_setprio(0);
    asm volatile("s_waitcnt lgkmcnt(0)" ::: "memory");  // ds_reads drained
    __builtin_amdgcn_s_barrier();       // safe to overwrite bc later
    bc = bc + 1 == NBUF ? 0 : bc + 1;
    bp = bp + 1 == NBUF ? 0 : bp + 1;
  }
#undef STAGE

  if (EPI == 0) {
    // cross -> dist -> weight -> swizzled LDS bounce (no partials).
    float ps[4], rt[4];
#pragma unroll
    for (int ni = 0; ni < 4; ++ni) {
      const int col = bn * BN + wn * 64 + ni * 16 + lr;
      ps[ni] = psq[col];
      rt[ni] = rtemp[col];  // log2e / effective_temp
    }
#pragma unroll
    for (int mi = 0; mi < MI; ++mi) {
#pragma unroll
      for (int j = 0; j < 4; ++j) {
        const int lrow = wm * (MI * 16) + mi * 16 + lg * 4 + j;
        const int grow = row0 + bm * BM + lrow;
        const float xq = xsq[grow];
#pragma unroll
        for (int ni = 0; ni < 4; ++ni) {
          const int lcol = wn * 64 + ni * 16 + lr;
          float d2 = xq + ps[ni] - 2.0f * acc[mi][ni][j];
          float dist = __builtin_amdgcn_sqrtf(fmaxf(d2, 0.0f));
          float w = __builtin_amdgcn_exp2f(-dist * rt[ni]);
          smem[lrow * BN + (((lcol >> 3) ^ (lrow & 7)) << 3) + (lcol & 7)] = f2bf(w);
        }
      }
    }
    __syncthreads();
    // coalesced cached copy-out (W re-read by wsum + pass B, L3-resident)
    constexpr int HB = BN / 8;
#pragma unroll
    for (int i = 0; i < BM * BN / 8 / NT; ++i) {
      const int id = i * NT + t;
      const int r = id / HB, h = id % HB;
      short8 v = *(const short8*)&smem[r * BN + ((h ^ (r & 7)) << 3)];
      *(short8*)&Wout[(size_t)(bm * BM + r) * ldOut + bn * BN + h * 8] = v;
    }
  } else {
    // scale by 1/denom at copy-out; bounce fp32 tile for full-line NT stores
    float* smemf = (float*)smem;
#pragma unroll
    for (int mi = 0; mi < MI; ++mi)
#pragma unroll
      for (int j = 0; j < 4; ++j) {
        const int lrow = wm * (MI * 16) + mi * 16 + lg * 4 + j;
#pragma unroll
        for (int ni = 0; ni < 4; ++ni) {
          const int lcol = wn * 64 + ni * 16 + lr;
          smemf[lrow * BN + (((lcol >> 2) ^ (lrow & 7)) << 2) + (lcol & 3)] =
              acc[mi][ni][j];
        }
      }
    __syncthreads();
    constexpr int HB4 = BN / 4;
#pragma unroll
    for (int i = 0; i < BM * BN / 4 / NT; ++i) {
      const int id = i * NT + t;
      const int r = id / HB4, h = id % HB4;
      const int grow = row0 + bm * BM + r;
      const float rd = 1.0f / (denin[grow] + 1e-8f);
      f32x4 v = *(const f32x4*)&smemf[r * BN + ((h ^ (r & 7)) << 2)];
      v *= rd;
      __builtin_nontemporal_store(v,
          (f32x4*)&outp[(size_t)grow * ldOut + bn * BN + h * 4]);
    }
  }
}

// denom[row] = sum_k W[row][k]; one wave per row, coalesced short8 reads
// (W just written by pass A -> mostly L3-resident).
__global__ void wsum(const unsigned short* __restrict__ W,
                     float* __restrict__ denom, int N) {
  const int lane = threadIdx.x & 63, wv = threadIdx.x >> 6;
  const int row = blockIdx.x * 4 + wv;
  const unsigned short* wr = W + (size_t)row * N;
  float s = 0.f;
  const int iters = N >> 9;  // N / (64 lanes * 8 elems)
  for (int i = 0; i < iters; ++i) {
    short8 v = *(const short8*)&wr[(i * 64 + lane) * 8];
#pragma unroll
    for (int e = 0; e < 8; ++e) s += bf2f(v[e]);
  }
  for (int off = 32; off; off >>= 1) s += __shfl_xor(s, off);
  if (lane == 0) denom[row] = s;
}

// Merged prep: rows [0,M) cast x; rows [M,M+N) cast pos; rows [M+N, ...)
// compute rtemp chunks (128 elems/block). 128 threads per block (D/4).
__global__ void prep_all(const float* __restrict__ x, const float* __restrict__ pos,
                         const float* __restrict__ temp, const float* __restrict__ nsc,
                         unsigned short* __restrict__ xb, unsigned short* __restrict__ pb,
                         float* __restrict__ xsq, float* __restrict__ psq,
                         float* __restrict__ rtemp, int D, int M, int N) {
  const int row = blockIdx.x;
  const int t = threadIdx.x;
  if (row >= M + N) {  // rtemp block
    const int i = (row - (M + N)) * 128 + t;
    if (i < N)
      rtemp[i] = 1.4426950408889634f / ((fabsf(temp[i]) + 0.1f) * nsc[i]);
    return;
  }
  const float* in;
  unsigned short* outb;
  float* sq;
  int r;
  if (row < M) {
    in = x; outb = xb; sq = xsq; r = row;
  } else {
    in = pos; outb = pb; sq = psq; r = row - M;
  }
  const float4 v = ((const float4*)(in + (size_t)r * D))[t];
  u16x4 o = {f2bf(v.x), f2bf(v.y), f2bf(v.z), f2bf(v.w)};
  *(u16x4*)(outb + (size_t)r * D + t * 4) = o;
  float s = v.x * v.x + v.y * v.y + v.z * v.z + v.w * v.w;
  for (int off = 32; off; off >>= 1) s += __shfl_xor(s, off);
  __shared__ float ws[16];
  if ((t & 63) == 0) ws[t >> 6] = s;
  __syncthreads();
  if (t == 0) {
    float tot = 0.f;
    const int nw = blockDim.x >> 6;
    for (int i = 0; i < nw; ++i) tot += ws[i];
    sq[r] = tot;
  }
}

// Transpose values [N][D] fp32 -> vT [D][N] bf16
__global__ void prep_vT(const float* __restrict__ vals, unsigned short* __restrict__ vT,
                        int N, int D) {
  __shared__ float tile[32][33];
  const int nt = blockIdx.x, dt = blockIdx.y;
  const int tx = threadIdx.x, ty = threadIdx.y;  // (32, 8)
#pragma unroll
  for (int i = 0; i < 4; ++i) {
    int r = nt * 32 + ty + i * 8;
    tile[ty + i * 8][tx] = vals[(size_t)r * D + dt * 32 + tx];
  }
  __syncthreads();
#pragma unroll
  for (int i = 0; i < 4; ++i) {
    int d = dt * 32 + ty + i * 8;
    vT[(size_t)d * N + nt * 32 + tx] = f2bf(tile[tx][ty + i * 8]);
  }
}

extern "C" void kernel_launch(void* const* d_in, const int* in_sizes, int n_in,
                              void* d_out, int out_size, void* d_ws, size_t ws_size,
                              hipStream_t stream) {
  const float* x = (const float*)d_in[0];
  const float* pos = (const float*)d_in[1];
  const float* vals = (const float*)d_in[2];
  const float* temp = (const float*)d_in[3];
  const float* nsc = (const float*)d_in[4];
  float* out = (float*)d_out;

  const int N = in_sizes[3];          // 4096
  const int D = in_sizes[1] / N;      // 512
  const int M = in_sizes[0] / D;      // 16384

  char* ws = (char*)d_ws;
  size_t off = 0;
  auto alloc = [&](size_t bytes) {
    void* p = ws + off;
    off = (off + bytes + 255) & ~(size_t)255;
    return p;
  };
  unsigned short* xb = (unsigned short*)alloc((size_t)M * D * 2);
  unsigned short* pb = (unsigned short*)alloc((size_t)N * D * 2);
  unsigned short* vT = (unsigned short*)alloc((size_t)D * N * 2);
  float* xsq = (float*)alloc((size_t)M * 4);
  float* psq = (float*)alloc((size_t)N * 4);
  float* rtemp = (float*)alloc((size_t)N * 4);
  float* denom = (float*)alloc((size_t)M * 4);

  size_t avail = ws_size > off ? ws_size - off : 0;
  long long mc_ll = (long long)(avail / ((size_t)N * 2));
  int Mc = (int)((mc_ll / 128) * 128);
  if (Mc > M) Mc = M;
  if (Mc < 128) Mc = 128;  // minimal fallback
  unsigned short* W = (unsigned short*)alloc((size_t)Mc * N * 2);

  prep_all<<<M + N + (N + 127) / 128, D / 4, 0, stream>>>(
      x, pos, temp, nsc, xb, pb, xsq, psq, rtemp, D, M, N);
  dim3 tg(N / 32, D / 32);
  prep_vT<<<tg, dim3(32, 8), 0, stream>>>(vals, vT, N, D);

  for (int row0 = 0; row0 < M; row0 += Mc) {
    const int mc = (M - row0) < Mc ? (M - row0) : Mc;
    // pass A: 128x256, BK=32, NBUF=3 (partial-free epilogue), 2 blk/CU
    const int g1 = (mc / 128) * (N / 256);
    rbf_gemm<0, 2, 4, 4, 32, 3><<<g1, 512, 0, stream>>>(
        xb + (size_t)row0 * D, pb, N, D, xsq, psq, rtemp, W,
        nullptr, nullptr, row0, N);
    // wsum: denom[row] = sum of W row (L3-resident read)
    wsum<<<mc / 4, 256, 0, stream>>>(W, denom + row0, N);
    // pass B: 128x256, BK=64, clean loop, denin from global
    const int g2 = (mc / 128) * (D / 256);
    rbf_gemm<1, 2, 4, 4, 64, 2><<<g2, 512, 0, stream>>>(
        W, vT, D, N, nullptr, nullptr, nullptr, nullptr,
        denom, out, row0, D);
  }
}

// Round 24
// 197.580 us; speedup vs baseline: 1.0055x; 1.0055x over previous
//
#include <hip/hip_runtime.h>
#include <hip/hip_bf16.h>

typedef __attribute__((ext_vector_type(8))) short short8;
typedef __attribute__((ext_vector_type(4))) float f32x4;
typedef __attribute__((ext_vector_type(4))) unsigned short u16x4;

__device__ __forceinline__ unsigned short f2bf(float f) {
  union { float f; unsigned u; } v; v.f = f;
  unsigned r = v.u + 0x7fffu + ((v.u >> 16) & 1u);
  return (unsigned short)(r >> 16);
}

__device__ __forceinline__ float bf2f(short s) {
  union { unsigned u; float f; } v;
  v.u = ((unsigned)(unsigned short)s) << 16;
  return v.f;
}

// C = A * Bt^T. WM*WN waves, wave-tile (MI*16) x 64, NBUF-deep circular LDS
// staging with counted vmcnt (prefetch stays in flight over MFMA), setprio.
// bn-MAJOR linear block mapping (L2 panel reuse per XCD).
// Pass A: EPI=0, WM=2,WN=4,MI=4,BK=32,NBUF=3 -> 128x256, 72 KB LDS,
//   2 blk/CU. Epilogue: w = exp2(-dist*rt2) -> W bf16 via swizzled LDS
//   bounce -> cached stores (pass B re-reads W). NO partials (denom is
//   computed by pass B, which reads every W-row element anyway).
// Pass B: EPI=1, WM=2,WN=4,MI=4,BK=64,NBUF=2 -> 128x256. wn==0 waves
//   accumulate den[row] = sum_k W[row][k] from the af fragments (each
//   (lg,ks,step) covers each chunk exactly once); lg-reduce via shfl_xor
//   16/32; 128 floats stashed in LDS past the fp32 bounce tile.
//   Epilogue: out fp32 * 1/(den+1e-8) via LDS bounce -> NT stores.
// LDS staging swizzle: row r (CH x 16B chunks) holds global chunk c^(r&CMASK)
// at slot c; applied global-side (linear gload_lds dest) + reader-side.
template <int EPI, int WM, int WN, int MI, int BK, int NBUF>
__global__ __launch_bounds__(WM * WN * 64, 4) void rbf_gemm(
    const unsigned short* __restrict__ A, const unsigned short* __restrict__ Bt,
    int Ncols, int K,
    const float* __restrict__ xsq, const float* __restrict__ psq,
    const float* __restrict__ rtemp, unsigned short* __restrict__ Wout,
    float* __restrict__ outp, int row0, int ldOut) {
  constexpr int NT = WM * WN * 64;       // threads per block
  constexpr int BM = WM * MI * 16;
  constexpr int BN = WN * 64;
  constexpr int CH = BK / 8;             // 16B chunks per row
  constexpr int CMASK = CH - 1;
  constexpr int AIT = BM * CH / NT;      // A staging iters
  constexpr int BIT = BN * CH / NT;      // B staging iters
  constexpr int LOADS = AIT + BIT;
  constexpr int KS = BK / 32;            // k-frags per step
  constexpr int ASZ = BM * BK;
  constexpr int TSZ = (BM + BN) * BK;    // elems per buffer
  constexpr int BOUNCE = EPI == 1 ? BM * BN * 2 : BM * BN;  // shorts
  constexpr int SBASE = NBUF * TSZ > BOUNCE ? NBUF * TSZ : BOUNCE;
  constexpr int SELEMS = SBASE + (EPI == 1 ? 256 : 0);  // +512B den stash
  __shared__ __align__(16) unsigned short smem[SELEMS];

  const int t = threadIdx.x;
  const int lane = t & 63, wid = t >> 6;
  const int wm = wid / WN, wn = wid % WN;
  const int lr = lane & 15, lg = lane >> 4;

  // bn-major mapping: consecutive blocks share bn and walk bm.
  const int nbm = gridDim.x / (Ncols / BN);
  const int bm = blockIdx.x % nbm;
  const int bn = blockIdx.x / nbm;

  const unsigned short* Ab = A + (size_t)bm * BM * K;
  const unsigned short* Bb = Bt + (size_t)bn * BN * K;

  // staging source pointers (swizzled chunk); bumped by +BK per stage
  const unsigned short* gA[AIT];
  const unsigned short* gB[BIT];
#pragma unroll
  for (int i = 0; i < AIT; ++i) {
    const int idx = i * NT + t;
    const int r = idx / CH, c = idx & CMASK;
    gA[i] = Ab + (size_t)r * K + ((c ^ (r & CMASK)) << 3);
  }
#pragma unroll
  for (int i = 0; i < BIT; ++i) {
    const int idx = i * NT + t;
    const int r = idx / CH, c = idx & CMASK;
    gB[i] = Bb + (size_t)r * K + ((c ^ (r & CMASK)) << 3);
  }
  const int dwave = wid << 9;  // wave-uniform LDS elem base (64 lanes * 16B)

  // fragment LDS element offsets (reader applies same swizzle)
  int offA[MI][KS], offB[4][KS];
#pragma unroll
  for (int mi = 0; mi < MI; ++mi) {
    const int ar = wm * (MI * 16) + mi * 16 + lr;
#pragma unroll
    for (int ks = 0; ks < KS; ++ks)
      offA[mi][ks] = ar * BK + ((((ks << 2) | lg) ^ (ar & CMASK)) << 3);
  }
#pragma unroll
  for (int ni = 0; ni < 4; ++ni) {
    const int br = wn * 64 + ni * 16 + lr;
#pragma unroll
    for (int ks = 0; ks < KS; ++ks)
      offB[ni][ks] = ASZ + br * BK + ((((ks << 2) | lg) ^ (br & CMASK)) << 3);
  }

  f32x4 acc[MI][4];
#pragma unroll
  for (int i = 0; i < MI; ++i)
#pragma unroll
    for (int j = 0; j < 4; ++j) acc[i][j] = (f32x4){0.f, 0.f, 0.f, 0.f};
  float den[MI];
#pragma unroll
  for (int i = 0; i < MI; ++i) den[i] = 0.f;

  // STAGE issues from current gA/gB then bumps them by BK.
#define STAGE(bo)                                                                      \
  do {                                                                                 \
    _Pragma("unroll")                                                                  \
    for (int i = 0; i < AIT; ++i) {                                                    \
      __builtin_amdgcn_global_load_lds(                                                \
          (const __attribute__((address_space(1))) void*)gA[i],                        \
          (__attribute__((address_space(3))) void*)(smem + (bo) + i * (NT * 8) + dwave), \
          16, 0, 0);                                                                   \
      gA[i] += BK;                                                                     \
    }                                                                                  \
    _Pragma("unroll")                                                                  \
    for (int i = 0; i < BIT; ++i) {                                                    \
      __builtin_amdgcn_global_load_lds(                                                \
          (const __attribute__((address_space(1))) void*)gB[i],                        \
          (__attribute__((address_space(3))) void*)(smem + (bo) + ASZ + i * (NT * 8) + dwave), \
          16, 0, 0);                                                                   \
      gB[i] += BK;                                                                     \
    }                                                                                  \
  } while (0)

  const int nsteps = K / BK;
  // prologue: issue NBUF-1 stages
#pragma unroll
  for (int p = 0; p < NBUF - 1; ++p)
    if (p < nsteps) STAGE(p * TSZ);

  int bc = 0, bp = (NBUF - 1) % NBUF;  // current / prefetch-dest buffers
  for (int s = 0; s < nsteps; ++s) {
    if (s + NBUF - 1 < nsteps) {
      STAGE(bp * TSZ);  // prefetch; stays in flight over MFMA
      asm volatile("s_waitcnt vmcnt(%0)" :: "i"((NBUF - 1) * LOADS) : "memory");
    } else if (NBUF >= 3 && s + 1 < nsteps) {
      asm volatile("s_waitcnt vmcnt(%0)" :: "i"(LOADS) : "memory");
    } else {
      asm volatile("s_waitcnt vmcnt(0)" ::: "memory");
    }
    __builtin_amdgcn_s_barrier();       // all waves' stage(s) landed
    const unsigned short* sb = smem + bc * TSZ;
    __builtin_amdgcn_s_setprio(1);
#pragma unroll
    for (int ks = 0; ks < KS; ++ks) {
      short8 af[MI], bf[4];
#pragma unroll
      for (int mi = 0; mi < MI; ++mi) af[mi] = *(const short8*)&sb[offA[mi][ks]];
#pragma unroll
      for (int ni = 0; ni < 4; ++ni) bf[ni] = *(const short8*)&sb[offB[ni][ks]];
#pragma unroll
      for (int mi = 0; mi < MI; ++mi)
#pragma unroll
        for (int ni = 0; ni < 4; ++ni)
          acc[mi][ni] = __builtin_amdgcn_mfma_f32_16x16x32_bf16(af[mi], bf[ni],
                                                                acc[mi][ni], 0, 0, 0);
      if (EPI == 1 && wn == 0) {  // denom: row-sum of A=W fragments
#pragma unroll
        for (int mi = 0; mi < MI; ++mi) {
          float d0 = 0.f;
#pragma unroll
          for (int e = 0; e < 8; ++e) d0 += bf2f(af[mi][e]);
          den[mi] += d0;
        }
      }
    }
    __builtin_amdgcn_s_setprio(0);
    asm volatile("s_waitcnt lgkmcnt(0)" ::: "memory");  // ds_reads drained
    __builtin_amdgcn_s_barrier();       // safe to overwrite bc later
    bc = bc + 1 == NBUF ? 0 : bc + 1;
    bp = bp + 1 == NBUF ? 0 : bp + 1;
  }
#undef STAGE

  if (EPI == 0) {
    // cross -> dist -> weight -> swizzled LDS bounce (no partials).
    float ps[4], rt[4];
#pragma unroll
    for (int ni = 0; ni < 4; ++ni) {
      const int col = bn * BN + wn * 64 + ni * 16 + lr;
      ps[ni] = psq[col];
      rt[ni] = rtemp[col];  // log2e / effective_temp
    }
#pragma unroll
    for (int mi = 0; mi < MI; ++mi) {
#pragma unroll
      for (int j = 0; j < 4; ++j) {
        const int lrow = wm * (MI * 16) + mi * 16 + lg * 4 + j;
        const int grow = row0 + bm * BM + lrow;
        const float xq = xsq[grow];
#pragma unroll
        for (int ni = 0; ni < 4; ++ni) {
          const int lcol = wn * 64 + ni * 16 + lr;
          float d2 = xq + ps[ni] - 2.0f * acc[mi][ni][j];
          float dist = __builtin_amdgcn_sqrtf(fmaxf(d2, 0.0f));
          float w = __builtin_amdgcn_exp2f(-dist * rt[ni]);
          smem[lrow * BN + (((lcol >> 3) ^ (lrow & 7)) << 3) + (lcol & 7)] = f2bf(w);
        }
      }
    }
    __syncthreads();
    // coalesced cached copy-out (W re-read by pass B)
    constexpr int HB = BN / 8;
#pragma unroll
    for (int i = 0; i < BM * BN / 8 / NT; ++i) {
      const int id = i * NT + t;
      const int r = id / HB, h = id % HB;
      short8 v = *(const short8*)&smem[r * BN + ((h ^ (r & 7)) << 3)];
      *(short8*)&Wout[(size_t)(bm * BM + r) * ldOut + bn * BN + h * 8] = v;
    }
  } else {
    // lg-reduce den (wn==0 waves hold each row's chunks across lg,ks,steps)
    float* dstash = (float*)(smem + SBASE);
    if (wn == 0) {
#pragma unroll
      for (int mi = 0; mi < MI; ++mi) {
        float d = den[mi];
        d += __shfl_xor(d, 16);
        d += __shfl_xor(d, 32);
        if (lg == 0) dstash[wm * (MI * 16) + mi * 16 + lr] = d;
      }
    }
    // scale by 1/den at copy-out; bounce fp32 tile for full-line NT stores
    float* smemf = (float*)smem;
    __syncthreads();  // dstash visible before copy-out phase
#pragma unroll
    for (int mi = 0; mi < MI; ++mi)
#pragma unroll
      for (int j = 0; j < 4; ++j) {
        const int lrow = wm * (MI * 16) + mi * 16 + lg * 4 + j;
#pragma unroll
        for (int ni = 0; ni < 4; ++ni) {
          const int lcol = wn * 64 + ni * 16 + lr;
          smemf[lrow * BN + (((lcol >> 2) ^ (lrow & 7)) << 2) + (lcol & 3)] =
              acc[mi][ni][j];
        }
      }
    __syncthreads();
    constexpr int HB4 = BN / 4;
#pragma unroll
    for (int i = 0; i < BM * BN / 4 / NT; ++i) {
      const int id = i * NT + t;
      const int r = id / HB4, h = id % HB4;
      const int grow = row0 + bm * BM + r;
      const float rd = 1.0f / (dstash[r] + 1e-8f);
      f32x4 v = *(const f32x4*)&smemf[r * BN + ((h ^ (r & 7)) << 2)];
      v *= rd;
      __builtin_nontemporal_store(v,
          (f32x4*)&outp[(size_t)grow * ldOut + bn * BN + h * 4]);
    }
  }
}

// Merged prep: rows [0,M) cast x; rows [M,M+N) cast pos; rows [M+N, ...)
// compute rtemp chunks (128 elems/block). 128 threads per block (D/4).
__global__ void prep_all(const float* __restrict__ x, const float* __restrict__ pos,
                         const float* __restrict__ temp, const float* __restrict__ nsc,
                         unsigned short* __restrict__ xb, unsigned short* __restrict__ pb,
                         float* __restrict__ xsq, float* __restrict__ psq,
                         float* __restrict__ rtemp, int D, int M, int N) {
  const int row = blockIdx.x;
  const int t = threadIdx.x;
  if (row >= M + N) {  // rtemp block
    const int i = (row - (M + N)) * 128 + t;
    if (i < N)
      rtemp[i] = 1.4426950408889634f / ((fabsf(temp[i]) + 0.1f) * nsc[i]);
    return;
  }
  const float* in;
  unsigned short* outb;
  float* sq;
  int r;
  if (row < M) {
    in = x; outb = xb; sq = xsq; r = row;
  } else {
    in = pos; outb = pb; sq = psq; r = row - M;
  }
  const float4 v = ((const float4*)(in + (size_t)r * D))[t];
  u16x4 o = {f2bf(v.x), f2bf(v.y), f2bf(v.z), f2bf(v.w)};
  *(u16x4*)(outb + (size_t)r * D + t * 4) = o;
  float s = v.x * v.x + v.y * v.y + v.z * v.z + v.w * v.w;
  for (int off = 32; off; off >>= 1) s += __shfl_xor(s, off);
  __shared__ float ws[16];
  if ((t & 63) == 0) ws[t >> 6] = s;
  __syncthreads();
  if (t == 0) {
    float tot = 0.f;
    const int nw = blockDim.x >> 6;
    for (int i = 0; i < nw; ++i) tot += ws[i];
    sq[r] = tot;
  }
}

// Transpose values [N][D] fp32 -> vT [D][N] bf16
__global__ void prep_vT(const float* __restrict__ vals, unsigned short* __restrict__ vT,
                        int N, int D) {
  __shared__ float tile[32][33];
  const int nt = blockIdx.x, dt = blockIdx.y;
  const int tx = threadIdx.x, ty = threadIdx.y;  // (32, 8)
#pragma unroll
  for (int i = 0; i < 4; ++i) {
    int r = nt * 32 + ty + i * 8;
    tile[ty + i * 8][tx] = vals[(size_t)r * D + dt * 32 + tx];
  }
  __syncthreads();
#pragma unroll
  for (int i = 0; i < 4; ++i) {
    int d = dt * 32 + ty + i * 8;
    vT[(size_t)d * N + nt * 32 + tx] = f2bf(tile[tx][ty + i * 8]);
  }
}

extern "C" void kernel_launch(void* const* d_in, const int* in_sizes, int n_in,
                              void* d_out, int out_size, void* d_ws, size_t ws_size,
                              hipStream_t stream) {
  const float* x = (const float*)d_in[0];
  const float* pos = (const float*)d_in[1];
  const float* vals = (const float*)d_in[2];
  const float* temp = (const float*)d_in[3];
  const float* nsc = (const float*)d_in[4];
  float* out = (float*)d_out;

  const int N = in_sizes[3];          // 4096
  const int D = in_sizes[1] / N;      // 512
  const int M = in_sizes[0] / D;      // 16384

  char* ws = (char*)d_ws;
  size_t off = 0;
  auto alloc = [&](size_t bytes) {
    void* p = ws + off;
    off = (off + bytes + 255) & ~(size_t)255;
    return p;
  };
  unsigned short* xb = (unsigned short*)alloc((size_t)M * D * 2);
  unsigned short* pb = (unsigned short*)alloc((size_t)N * D * 2);
  unsigned short* vT = (unsigned short*)alloc((size_t)D * N * 2);
  float* xsq = (float*)alloc((size_t)M * 4);
  float* psq = (float*)alloc((size_t)N * 4);
  float* rtemp = (float*)alloc((size_t)N * 4);

  size_t avail = ws_size > off ? ws_size - off : 0;
  long long mc_ll = (long long)(avail / ((size_t)N * 2));
  int Mc = (int)((mc_ll / 128) * 128);
  if (Mc > M) Mc = M;
  if (Mc < 128) Mc = 128;  // minimal fallback
  unsigned short* W = (unsigned short*)alloc((size_t)Mc * N * 2);

  prep_all<<<M + N + (N + 127) / 128, D / 4, 0, stream>>>(
      x, pos, temp, nsc, xb, pb, xsq, psq, rtemp, D, M, N);
  dim3 tg(N / 32, D / 32);
  prep_vT<<<tg, dim3(32, 8), 0, stream>>>(vals, vT, N, D);

  for (int row0 = 0; row0 < M; row0 += Mc) {
    const int mc = (M - row0) < Mc ? (M - row0) : Mc;
    // pass A: 128x256, BK=32, NBUF=3 (2-deep prefetch), 2 blk/CU
    const int g1 = (mc / 128) * (N / 256);
    rbf_gemm<0, 2, 4, 4, 32, 3><<<g1, 512, 0, stream>>>(
        xb + (size_t)row0 * D, pb, N, D, xsq, psq, rtemp, W,
        nullptr, row0, N);
    // pass B: 128x256, BK=64; computes denom internally from W fragments
    const int g2 = (mc / 128) * (D / 256);
    rbf_gemm<1, 2, 4, 4, 64, 2><<<g2, 512, 0, stream>>>(
        W, vT, D, N, nullptr, nullptr, nullptr, nullptr,
        out, row0, D);
  }
}